// Round 8
// baseline (1523.413 us; speedup 1.0000x reference)
//
#include <hip/hip_runtime.h>
#include <cstdint>
#include <cstddef>

// ---------------------------------------------------------------------------
// GATFuse. R3 -> R4 changes (determinism fix; R3 failed POST-TIMING check):
//  - sortrow_k: canonical (ascending) order for each CSR row. fill_k's atomic
//    slot assignment is a different permutation each graph replay -> fp sum
//    order drifted -> post-timing divergence. Sorted rows => bit-identical
//    output every call.
//  - BN stats: atomic doubles replaced by per-block partials + fixed-tree
//    reduce (deterministic).
//  - expf (precise) instead of __expf in softmax paths: accuracy margin.
// Perf design unchanged from R3 (1207 us): agg 2-4 edges/iter row gather,
// gemm K-split 2x64 (32KB LDS).
// ---------------------------------------------------------------------------

#define NLAYERS 3
#define BN_BLOCKS 256

__device__ __forceinline__ float lrelu(float a){ return a > 0.f ? a : 0.2f*a; }

__device__ __forceinline__ float wsum(float v){
#pragma unroll
  for (int o = 32; o > 0; o >>= 1) v += __shfl_xor(v, o);
  return v;
}

// ----------------------------- utility kernels -----------------------------
__global__ void zero_k(int* __restrict__ p, int n){
  int i = blockIdx.x*blockDim.x + threadIdx.x;
  if (i < n) p[i] = 0;
}
__global__ void copy_k(const int* __restrict__ a, int* __restrict__ b, int n){
  int i = blockIdx.x*blockDim.x + threadIdx.x;
  if (i < n) b[i] = a[i];
}
__global__ void count_k(const int* __restrict__ dst, int E, int* __restrict__ cnt){
  int e = blockIdx.x*blockDim.x + threadIdx.x;
  if (e < E) atomicAdd(&cnt[dst[e]], 1);
}
__global__ __launch_bounds__(1024) void scanA_k(const int* __restrict__ cnt,
    int* __restrict__ excl, int* __restrict__ bsum, int N){
  __shared__ int wpart[16];
  const int tid = threadIdx.x, lane = tid & 63, w = tid >> 6;
  const int i = blockIdx.x*1024 + tid;
  const int v = (i < N) ? cnt[i] : 0;
  int s = v;
#pragma unroll
  for (int o = 1; o < 64; o <<= 1){ int t = __shfl_up(s, o); if (lane >= o) s += t; }
  if (lane == 63) wpart[w] = s;
  __syncthreads();
  if (w == 0){
    int t = (lane < 16) ? wpart[lane] : 0;
#pragma unroll
    for (int o = 1; o < 16; o <<= 1){ int u = __shfl_up(t, o); if (lane >= o) t += u; }
    if (lane < 16) wpart[lane] = t;
  }
  __syncthreads();
  const int woff = (w > 0) ? wpart[w-1] : 0;
  const int incl = s + woff;
  if (i < N) excl[i] = incl - v;
  if (tid == 1023) bsum[blockIdx.x] = incl;
}
__global__ void scanB_k(const int* __restrict__ bsum, int* __restrict__ boff, int nb){
  const int lane = threadIdx.x;
  const int v = (lane < nb) ? bsum[lane] : 0;
  int s = v;
#pragma unroll
  for (int o = 1; o < 64; o <<= 1){ int t = __shfl_up(s, o); if (lane >= o) s += t; }
  if (lane < nb) boff[lane] = s - v;
  if (lane == nb-1) boff[nb] = s;
}
__global__ __launch_bounds__(1024) void scanC_k(int* __restrict__ rp,
    const int* __restrict__ boff, int N, int nb){
  const int i = blockIdx.x*1024 + threadIdx.x;
  if (i < N) rp[i] += boff[blockIdx.x];
  if (i == 0) rp[N] = boff[nb];
}
__global__ void fill_k(const int* __restrict__ src, const int* __restrict__ dst, int E,
                       int* __restrict__ pos, int* __restrict__ col){
  int e = blockIdx.x*blockDim.x + threadIdx.x;
  if (e < E){
    int d = dst[e];
    int p = atomicAdd(&pos[d], 1);
    col[p] = src[e];
  }
}
// canonical per-row order: ascending insertion sort (rows ~Poisson(16)).
// Makes CSR content replay-invariant despite atomic slot assignment.
__global__ void sortrow_k(const int* __restrict__ rp, int* __restrict__ col, int N){
  const int n = blockIdx.x*blockDim.x + threadIdx.x;
  if (n >= N) return;
  const int b = rp[n], e = rp[n+1];
  for (int i = b + 1; i < e; ++i){
    const int key = col[i];
    int j = i - 1;
    while (j >= b && col[j] > key){ col[j+1] = col[j]; --j; }
    col[j+1] = key;
  }
}

// ----------------------------- GEMM  h = A(Nx128) @ W(128xM) ----------------
// 64x64 tile per 256-thread block, K staged in 2 halves of 64 (32KB LDS).
// BN(scale,shift)+ReLU optionally applied to A while staging. Epilogue
// computes per-head attention dots (block (.,y) owns head y fully).
__global__ __launch_bounds__(256) void gemm_k(const float* __restrict__ A,
    const float* __restrict__ W, float* __restrict__ O,
    const float* __restrict__ bnsc, const float* __restrict__ bnsh,
    const float* __restrict__ atts, const float* __restrict__ attd,
    float* __restrict__ als, float* __restrict__ ald, int N, int M){
  __shared__ float xs[64][64];    // [k'][swizzled row]
  __shared__ float wsh[64][64];   // [k'][col]
  const int tid = threadIdx.x;
  const int row0 = blockIdx.x*64, col0 = blockIdx.y*64;
  const int HS = gridDim.y;       // heads == col blocks
  const int ty = tid >> 4, tx = tid & 15;
  float acc[4][4] = {};

  for (int kk = 0; kk < 128; kk += 64){
    // stage W rows kk..kk+63 (4 x float4 per thread = 64x64)
    {
      const int c4 = (tid & 15)*4;
#pragma unroll
      for (int p = 0; p < 4; ++p){
        const int k = p*16 + (tid >> 4);
        *reinterpret_cast<float4*>(&wsh[k][c4]) =
            *reinterpret_cast<const float4*>(&W[(size_t)(kk + k)*M + col0 + c4]);
      }
    }
    // stage x transposed with XOR swizzle
    {
      const int k4 = (tid & 15)*4;           // local k' base (0..60)
      const int rbase = tid >> 4;            // 0..15
#pragma unroll
      for (int p = 0; p < 4; ++p){
        const int rr = p*16 + rbase;
        int gr = row0 + rr; if (gr > N-1) gr = N-1;
        float4 xv = *reinterpret_cast<const float4*>(&A[(size_t)gr*128 + kk + k4]);
        float xq[4] = {xv.x, xv.y, xv.z, xv.w};
        if (bnsc != nullptr){
#pragma unroll
          for (int q = 0; q < 4; ++q)
            xq[q] = fmaxf(xq[q]*bnsc[kk + k4 + q] + bnsh[kk + k4 + q], 0.f);
        }
#pragma unroll
        for (int q = 0; q < 4; ++q){
          const int k = k4 + q;
          const int swz = ((k >> 2) & 15) << 2;
          xs[k][rr ^ swz] = xq[q];
        }
      }
    }
    __syncthreads();
#pragma unroll 8
    for (int k = 0; k < 64; ++k){
      const int swz = ((k >> 2) & 15) << 2;
      const int xr = (ty*4) ^ swz;
      const float4 xv = *reinterpret_cast<const float4*>(&xs[k][xr]);
      const float2 w0 = *reinterpret_cast<const float2*>(&wsh[k][2*tx]);
      const float2 w1 = *reinterpret_cast<const float2*>(&wsh[k][32 + 2*tx]);
      const float xq[4] = {xv.x, xv.y, xv.z, xv.w};
#pragma unroll
      for (int i = 0; i < 4; ++i){
        acc[i][0] += xq[i]*w0.x;
        acc[i][1] += xq[i]*w0.y;
        acc[i][2] += xq[i]*w1.x;
        acc[i][3] += xq[i]*w1.y;
      }
    }
    __syncthreads();
  }
  // ---- alpha epilogue: per-head dots with att_src/att_dst ----
  {
    const float* as = atts + col0;
    const float* ad = attd + col0;
    const float a_s0 = as[2*tx],      a_s1 = as[2*tx + 1];
    const float a_s2 = as[32 + 2*tx], a_s3 = as[33 + 2*tx];
    const float a_d0 = ad[2*tx],      a_d1 = ad[2*tx + 1];
    const float a_d2 = ad[32 + 2*tx], a_d3 = ad[33 + 2*tx];
#pragma unroll
    for (int i = 0; i < 4; ++i){
      float ps = acc[i][0]*a_s0 + acc[i][1]*a_s1 + acc[i][2]*a_s2 + acc[i][3]*a_s3;
      float pd = acc[i][0]*a_d0 + acc[i][1]*a_d1 + acc[i][2]*a_d2 + acc[i][3]*a_d3;
#pragma unroll
      for (int o = 1; o < 16; o <<= 1){
        ps += __shfl_xor(ps, o);
        pd += __shfl_xor(pd, o);
      }
      const int r = row0 + ty*4 + i;
      if (tx == 0 && r < N){
        als[(size_t)r*HS + blockIdx.y] = ps;
        ald[(size_t)r*HS + blockIdx.y] = pd;
      }
    }
  }
#pragma unroll
  for (int i = 0; i < 4; ++i){
    const int r = row0 + ty*4 + i;
    if (r < N){
      float2* o2 = reinterpret_cast<float2*>(&O[(size_t)r*M + col0]);
      o2[tx]      = make_float2(acc[i][0], acc[i][1]);
      o2[16 + tx] = make_float2(acc[i][2], acc[i][3]);
    }
  }
}

// -------- per-node softmax over incoming edges + weighted gather-sum --------
// Phase 1: online (max,sum) over edges, wave-parallel.
// Phase 2: row gather; 32 lanes x float4 = full row => 2 edges/iter (H=2),
//          16 lanes x float4 = full row => 4 edges/iter (H=1).
//          Self-term carried only by edge-group 0.
template<int H>
__global__ __launch_bounds__(256) void agg_k(const float* __restrict__ h,
    const float* __restrict__ als, const float* __restrict__ ald,
    const int* __restrict__ rp, const int* __restrict__ col,
    const float* __restrict__ bias, float* __restrict__ out, int N){
  const int lane = threadIdx.x & 63;
  const int n = blockIdx.x*4 + (threadIdx.x >> 6);
  if (n >= N) return;
  const int beg = rp[n], end = rp[n+1];
  float as0, as1 = 0.f, ad0, ad1 = 0.f;
  if (H == 2){
    const float2 a = ((const float2*)als)[n];
    const float2 d = ((const float2*)ald)[n];
    as0 = a.x; as1 = a.y; ad0 = d.x; ad1 = d.y;
  } else { as0 = als[n]; ad0 = ald[n]; }
  const float self0 = lrelu(as0 + ad0);
  const float self1 = (H == 2) ? lrelu(as1 + ad1) : 0.f;
  // ---- phase 1: online softmax (m, p) per lane, then wave combine ----
  float m0 = self0, p0 = (lane == 0) ? 1.f : 0.f;
  float m1 = self1, p1 = (lane == 0) ? 1.f : 0.f;
  for (int i = beg + lane; i < end; i += 64){
    const int s = col[i];
    if (H == 2){
      const float2 a = ((const float2*)als)[s];
      const float al0 = lrelu(a.x + ad0);
      const float al1 = lrelu(a.y + ad1);
      if (al0 > m0){ p0 = p0*expf(m0 - al0) + 1.f; m0 = al0; }
      else p0 += expf(al0 - m0);
      if (al1 > m1){ p1 = p1*expf(m1 - al1) + 1.f; m1 = al1; }
      else p1 += expf(al1 - m1);
    } else {
      const float al0 = lrelu(als[s] + ad0);
      if (al0 > m0){ p0 = p0*expf(m0 - al0) + 1.f; m0 = al0; }
      else p0 += expf(al0 - m0);
    }
  }
#pragma unroll
  for (int o = 1; o < 64; o <<= 1){
    const float om0 = __shfl_xor(m0, o), op0 = __shfl_xor(p0, o);
    const float nm0 = fmaxf(m0, om0);
    p0 = p0*expf(m0 - nm0) + op0*expf(om0 - nm0); m0 = nm0;
    if (H == 2){
      const float om1 = __shfl_xor(m1, o), op1 = __shfl_xor(p1, o);
      const float nm1 = fmaxf(m1, om1);
      p1 = p1*expf(m1 - nm1) + op1*expf(om1 - nm1); m1 = nm1;
    }
  }
  const float inv0 = 1.f/(p0 + 1e-16f);
  const float inv1 = (H == 2) ? 1.f/(p1 + 1e-16f) : 0.f;

  // ---- phase 2: gather; float4 per lane ----
  const float4* h4 = (const float4*)h;
  if (H == 2){
    const int sub = lane & 31;            // owns cols 4*sub..4*sub+3
    const int half = lane >> 5;           // which edge of the pair
    const float csel = (sub < 16) ? expf(self0 - m0)*inv0 : expf(self1 - m1)*inv1;
    const float cs = (half == 0) ? csel : 0.f;   // self only in group 0
    const float4 hv = h4[(size_t)n*32 + sub];
    float ax = cs*hv.x, ay = cs*hv.y, az = cs*hv.z, aw = cs*hv.w;
    for (int base = beg; base < end; base += 64){
      const int idx = base + lane;
      int sv = n; float c0v = 0.f, c1v = 0.f;
      if (idx < end){
        sv = col[idx];
        const float2 a = ((const float2*)als)[sv];
        c0v = expf(lrelu(a.x + ad0) - m0)*inv0;
        c1v = expf(lrelu(a.y + ad1) - m1)*inv1;
      }
      const int cnt = min(64, end - base);
      const int iters = (cnt + 1) >> 1;
      for (int j = 0; j < iters; ++j){
        const int e = 2*j + half;
        const int   src = __shfl(sv, e);
        const float cc0 = __shfl(c0v, e);
        const float cc1 = __shfl(c1v, e);
        const float c = (sub < 16) ? cc0 : cc1;
        const float4 hvv = h4[(size_t)src*32 + sub];
        ax += c*hvv.x; ay += c*hvv.y; az += c*hvv.z; aw += c*hvv.w;
      }
    }
    // combine the two half-wave partials (same cols, different edges)
    ax += __shfl_xor(ax, 32); ay += __shfl_xor(ay, 32);
    az += __shfl_xor(az, 32); aw += __shfl_xor(aw, 32);
    if (lane < 32){
      const float4 bv = ((const float4*)bias)[sub];
      float4 o4 = make_float4(ax + bv.x, ay + bv.y, az + bv.z, aw + bv.w);
      ((float4*)out)[(size_t)n*32 + sub] = o4;
    }
  } else {
    const int sub = lane & 15;            // owns cols 4*sub..4*sub+3 (of 64)
    const int quad = lane >> 4;           // which edge of the quad
    const float cs = (quad == 0) ? expf(self0 - m0)*inv0 : 0.f;  // self once
    const float4 hv = h4[(size_t)n*16 + sub];
    float ax = cs*hv.x, ay = cs*hv.y, az = cs*hv.z, aw = cs*hv.w;
    for (int base = beg; base < end; base += 64){
      const int idx = base + lane;
      int sv = n; float c0v = 0.f;
      if (idx < end){
        sv = col[idx];
        c0v = expf(lrelu(als[sv] + ad0) - m0)*inv0;
      }
      const int cnt = min(64, end - base);
      const int iters = (cnt + 3) >> 2;
      for (int j = 0; j < iters; ++j){
        const int e = 4*j + quad;
        const int   src = __shfl(sv, e);
        const float cc  = __shfl(c0v, e);
        const float4 hvv = h4[(size_t)src*16 + sub];
        ax += cc*hvv.x; ay += cc*hvv.y; az += cc*hvv.z; aw += cc*hvv.w;
      }
    }
    ax += __shfl_xor(ax, 16); ay += __shfl_xor(ay, 16);
    az += __shfl_xor(az, 16); aw += __shfl_xor(aw, 16);
    ax += __shfl_xor(ax, 32); ay += __shfl_xor(ay, 32);
    az += __shfl_xor(az, 32); aw += __shfl_xor(aw, 32);
    if (lane < 16){
      const float4 bv = ((const float4*)bias)[sub];
      float4 o4 = make_float4(ax + bv.x, ay + bv.y, az + bv.z, aw + bv.w);
      ((float4*)out)[(size_t)n*16 + sub] = o4;
    }
  }
}

// ------------------------------- batch norm ---------------------------------
// Deterministic two-stage: per-block partials (fixed slots) + fixed-tree reduce.
__global__ __launch_bounds__(128) void bn_stats_k(const float* __restrict__ x, int N,
                                                  double* __restrict__ part){
  const int c = threadIdx.x;           // 128 columns
  double s = 0.0, s2 = 0.0;
  for (int r = blockIdx.x; r < N; r += gridDim.x){
    const float v = x[(size_t)r*128 + c];
    s += v; s2 += (double)v*(double)v;
  }
  part[(size_t)blockIdx.x*256 + c]       = s;
  part[(size_t)blockIdx.x*256 + 128 + c] = s2;
}
// block c reduces column c's partials in a fixed tree; emits scale/shift.
__global__ __launch_bounds__(64) void bnfin_k(const double* __restrict__ part,
    const float* __restrict__ g, const float* __restrict__ b,
    float* __restrict__ sc, float* __restrict__ sh, int N){
  const int c = blockIdx.x;
  const int l = threadIdx.x;
  double s = 0.0, s2 = 0.0;
  for (int i = l; i < BN_BLOCKS; i += 64){
    s  += part[(size_t)i*256 + c];
    s2 += part[(size_t)i*256 + 128 + c];
  }
#pragma unroll
  for (int o = 32; o > 0; o >>= 1){
    s  += __shfl_xor(s, o);
    s2 += __shfl_xor(s2, o);
  }
  if (l == 0){
    const double mu  = s/(double)N;
    const double var = s2/(double)N - mu*mu;
    const float scale = rsqrtf((float)var + 1e-5f)*g[c];
    sc[c] = scale;
    sh[c] = b[c] - (float)mu*scale;
  }
}

// ------------------------------ readout -------------------------------------
__global__ __launch_bounds__(256) void pred_k(const float* __restrict__ f0,
    const float* __restrict__ f1, const float* __restrict__ Wo,
    float* __restrict__ pred, int N){
  const int lane = threadIdx.x & 63;
  const int n = blockIdx.x*4 + (threadIdx.x >> 6);
  if (n >= N) return;
  const float xf = (f0[(size_t)n*64 + lane] + f1[(size_t)n*64 + lane])*0.5f;
  const float p = wsum(xf*Wo[lane]);
  if (lane == 0) pred[n] = p;
}
__global__ __launch_bounds__(64) void segred_k(const float* __restrict__ pred,
    const int* __restrict__ bid, const float* __restrict__ bo,
    float* __restrict__ out, int N){
  const int g = blockIdx.x;
  int lo = 0, hi = N;
  while (lo < hi){ const int mid = (lo + hi) >> 1; if (bid[mid] < g) lo = mid + 1; else hi = mid; }
  const int s0 = lo;
  hi = N;
  while (lo < hi){ const int mid = (lo + hi) >> 1; if (bid[mid] < g + 1) lo = mid + 1; else hi = mid; }
  const int s1 = lo;
  float s = 0.f;
  for (int i = s0 + threadIdx.x; i < s1; i += 64) s += pred[i];
  s = wsum(s);
  if (threadIdx.x == 0)
    out[g] = (s1 > s0) ? s/(float)(s1 - s0) + bo[0] : 0.f;
}

// ---------------------------------------------------------------------------
extern "C" void kernel_launch(void* const* d_in, const int* in_sizes, int n_in,
                              void* d_out, int out_size, void* d_ws, size_t ws_size,
                              hipStream_t stream) {
  const int N = in_sizes[0]/128;      // 50000
  const int E = in_sizes[1]/2;        // 800000
  const int G = out_size;             // 512

  const float* x    = (const float*)d_in[0];
  const int*   eisc = (const int*)d_in[1];
  const int*   eifc = (const int*)d_in[2];
  const int*   bid  = (const int*)d_in[3];
  const float* Ws   = (const float*)d_in[4];
  const float* atts = (const float*)d_in[5];
  const float* attd = (const float*)d_in[6];
  const float* bgat = (const float*)d_in[7];
  const float* bng  = (const float*)d_in[8];
  const float* bnb  = (const float*)d_in[9];
  const float* Wf   = (const float*)d_in[10];
  const float* afs  = (const float*)d_in[11];
  const float* afd  = (const float*)d_in[12];
  const float* bf   = (const float*)d_in[13];
  const float* Wo   = (const float*)d_in[14];
  const float* bo   = (const float*)d_in[15];
  float* out = (float*)d_out;

  char* wp = (char*)d_ws;
  auto grab = [&](size_t bytes)->char* {
    uintptr_t p = ((uintptr_t)wp + 255) & ~(uintptr_t)255;
    wp = (char*)(p + bytes);
    return (char*)p;
  };
  // zeroed region (contiguous, single zero kernel): CSR counters only
  char* zbase = (char*)(((uintptr_t)d_ws + 255) & ~(uintptr_t)255);
  int*    cntA  = (int*)grab((size_t)N*4);
  int*    cntB  = (int*)grab((size_t)N*4);
  const int zwords = (int)(((size_t)(wp - zbase)) / 4);
  // non-zeroed scratch
  double* part  = (double*)grab((size_t)BN_BLOCKS*256*8);
  int*   rp_sc  = (int*)grab((size_t)(N+1)*4);
  int*   rp_fc  = (int*)grab((size_t)(N+1)*4);
  int*   col_sc = (int*)grab((size_t)E*4);
  int*   col_fc = (int*)grab((size_t)E*4);
  int*   bsum   = (int*)grab(64*4);
  int*   boff   = (int*)grab(65*4);
  float* hb     = (float*)grab((size_t)N*128*4);
  float* x0b    = (float*)grab((size_t)N*128*4);
  float* x1b    = (float*)grab((size_t)N*128*4);
  float* alsb   = (float*)grab((size_t)N*2*4);
  float* aldb   = (float*)grab((size_t)N*2*4);
  float* bnsc   = (float*)grab((size_t)6*128*4);
  float* bnsh   = (float*)grab((size_t)6*128*4);
  float* pred   = alsb;               // reuse (dead by readout time)
  (void)ws_size; (void)n_in;

  zero_k<<<(zwords + 255)/256, 256, 0, stream>>>((int*)zbase, zwords);

  const int EB = (E + 255)/256;
  const int NB = (N + 255)/256;
  const int SB = (N + 1023)/1024;     // 49
  // ---- CSR for sc edge set (dst-major) ----
  count_k<<<EB, 256, 0, stream>>>(eisc + E, E, cntA);
  count_k<<<EB, 256, 0, stream>>>(eifc + E, E, cntB);
  scanA_k<<<SB, 1024, 0, stream>>>(cntA, rp_sc, bsum, N);
  scanB_k<<<1, 64, 0, stream>>>(bsum, boff, SB);
  scanC_k<<<SB, 1024, 0, stream>>>(rp_sc, boff, N, SB);
  copy_k<<<NB, 256, 0, stream>>>(rp_sc, cntA, N);
  fill_k<<<EB, 256, 0, stream>>>(eisc, eisc + E, E, cntA, col_sc);
  sortrow_k<<<NB, 256, 0, stream>>>(rp_sc, col_sc, N);
  // ---- CSR for fc edge set ----
  scanA_k<<<SB, 1024, 0, stream>>>(cntB, rp_fc, bsum, N);
  scanB_k<<<1, 64, 0, stream>>>(bsum, boff, SB);
  scanC_k<<<SB, 1024, 0, stream>>>(rp_fc, boff, N, SB);
  copy_k<<<NB, 256, 0, stream>>>(rp_fc, cntB, N);
  fill_k<<<EB, 256, 0, stream>>>(eifc, eifc + E, E, cntB, col_fc);
  sortrow_k<<<NB, 256, 0, stream>>>(rp_fc, col_fc, N);

  const int NB4 = (N + 3)/4;          // wave-per-node grids
  const dim3 gg2((N + 63)/64, 2), gg1((N + 63)/64, 1);
  const float* cur0 = x;
  const float* cur1 = x;
  for (int l = 0; l < NLAYERS; ++l){
    const float* Wl = Ws + (size_t)l*128*128;
    const float* as = atts + l*128;
    const float* ad = attd + l*128;
    const float* bg = bgat + l*128;
    // BN params of PREVIOUS layer fused into this gemm's A staging (l==0: none)
    const float* sc0 = (l == 0) ? nullptr : bnsc + ((l-1)*2 + 0)*128;
    const float* sh0 = (l == 0) ? nullptr : bnsh + ((l-1)*2 + 0)*128;
    const float* sc1 = (l == 0) ? nullptr : bnsc + ((l-1)*2 + 1)*128;
    const float* sh1 = (l == 0) ? nullptr : bnsh + ((l-1)*2 + 1)*128;

    // branch 0 (sc)
    gemm_k<<<gg2, 256, 0, stream>>>(cur0, Wl, hb, sc0, sh0, as, ad, alsb, aldb, N, 128);
    agg_k<2><<<NB4, 256, 0, stream>>>(hb, alsb, aldb, rp_sc, col_sc, bg, x0b, N);
    bn_stats_k<<<BN_BLOCKS, 128, 0, stream>>>(x0b, N, part);
    bnfin_k<<<128, 64, 0, stream>>>(part, bng + l*128, bnb + l*128,
                                    bnsc + (l*2 + 0)*128, bnsh + (l*2 + 0)*128, N);
    // branch 1 (fc): layer 0 shares x AND W -> reuse hb/alsb/aldb from branch 0
    if (l != 0)
      gemm_k<<<gg2, 256, 0, stream>>>(cur1, Wl, hb, sc1, sh1, as, ad, alsb, aldb, N, 128);
    agg_k<2><<<NB4, 256, 0, stream>>>(hb, alsb, aldb, rp_fc, col_fc, bg, x1b, N);
    bn_stats_k<<<BN_BLOCKS, 128, 0, stream>>>(x1b, N, part);
    bnfin_k<<<128, 64, 0, stream>>>(part, bng + l*128, bnb + l*128,
                                    bnsc + (l*2 + 1)*128, bnsh + (l*2 + 1)*128, N);
    cur0 = x0b;
    cur1 = x1b;
  }
  // final convs (H=1, C=64); BN of layer 2 fused into gemm A staging.
  // agg outputs reuse x0b/x1b as [N][64] (safe: gemm consumed them already).
  gemm_k<<<gg1, 256, 0, stream>>>(cur0, Wf, hb, bnsc + 4*128, bnsh + 4*128,
                                  afs, afd, alsb, aldb, N, 64);
  agg_k<1><<<NB4, 256, 0, stream>>>(hb, alsb, aldb, rp_sc, col_sc, bf, x0b, N);

  gemm_k<<<gg1, 256, 0, stream>>>(cur1, Wf, hb, bnsc + 5*128, bnsh + 5*128,
                                  afs, afd, alsb, aldb, N, 64);
  agg_k<1><<<NB4, 256, 0, stream>>>(hb, alsb, aldb, rp_fc, col_fc, bf, x1b, N);

  // fuse + readout + per-graph mean (atomic-free: sorted-segment reduce)
  pred_k<<<NB4, 256, 0, stream>>>(x0b, x1b, Wo, pred, N);
  segred_k<<<G, 64, 0, stream>>>(pred, bid, bo, out, N);
}

// Round 10
// 1361.354 us; speedup vs baseline: 1.1190x; 1.1190x over previous
//
#include <hip/hip_runtime.h>
#include <cstdint>
#include <cstddef>

// ---------------------------------------------------------------------------
// GATFuse. R4 -> R5 changes (resubmit; broker timeout, never ran):
//  - sortrow_k: serial per-thread insertion sort (94us, 5% occupancy) replaced
//    by wave-per-node 64-wide bitonic sort in registers (21 shfl_xor stages).
//    Deterministic lane-0 insertion fallback for deg>64 (P ~ 1e-20).
//  - __expf restored (R3's post-timing failure was summation-order drift, not
//    exp precision; execution is now bit-deterministic so replay == initial).
// Carried from R4: canonical CSR row order, deterministic two-stage BN.
// Carried from R3: agg 2-4 edges/iter row gather, gemm K-split 2x64.
// ---------------------------------------------------------------------------

#define NLAYERS 3
#define BN_BLOCKS 256

__device__ __forceinline__ float lrelu(float a){ return a > 0.f ? a : 0.2f*a; }

__device__ __forceinline__ float wsum(float v){
#pragma unroll
  for (int o = 32; o > 0; o >>= 1) v += __shfl_xor(v, o);
  return v;
}

// ----------------------------- utility kernels -----------------------------
__global__ void zero_k(int* __restrict__ p, int n){
  int i = blockIdx.x*blockDim.x + threadIdx.x;
  if (i < n) p[i] = 0;
}
__global__ void copy_k(const int* __restrict__ a, int* __restrict__ b, int n){
  int i = blockIdx.x*blockDim.x + threadIdx.x;
  if (i < n) b[i] = a[i];
}
__global__ void count_k(const int* __restrict__ dst, int E, int* __restrict__ cnt){
  int e = blockIdx.x*blockDim.x + threadIdx.x;
  if (e < E) atomicAdd(&cnt[dst[e]], 1);
}
__global__ __launch_bounds__(1024) void scanA_k(const int* __restrict__ cnt,
    int* __restrict__ excl, int* __restrict__ bsum, int N){
  __shared__ int wpart[16];
  const int tid = threadIdx.x, lane = tid & 63, w = tid >> 6;
  const int i = blockIdx.x*1024 + tid;
  const int v = (i < N) ? cnt[i] : 0;
  int s = v;
#pragma unroll
  for (int o = 1; o < 64; o <<= 1){ int t = __shfl_up(s, o); if (lane >= o) s += t; }
  if (lane == 63) wpart[w] = s;
  __syncthreads();
  if (w == 0){
    int t = (lane < 16) ? wpart[lane] : 0;
#pragma unroll
    for (int o = 1; o < 16; o <<= 1){ int u = __shfl_up(t, o); if (lane >= o) t += u; }
    if (lane < 16) wpart[lane] = t;
  }
  __syncthreads();
  const int woff = (w > 0) ? wpart[w-1] : 0;
  const int incl = s + woff;
  if (i < N) excl[i] = incl - v;
  if (tid == 1023) bsum[blockIdx.x] = incl;
}
__global__ void scanB_k(const int* __restrict__ bsum, int* __restrict__ boff, int nb){
  const int lane = threadIdx.x;
  const int v = (lane < nb) ? bsum[lane] : 0;
  int s = v;
#pragma unroll
  for (int o = 1; o < 64; o <<= 1){ int t = __shfl_up(s, o); if (lane >= o) s += t; }
  if (lane < nb) boff[lane] = s - v;
  if (lane == nb-1) boff[nb] = s;
}
__global__ __launch_bounds__(1024) void scanC_k(int* __restrict__ rp,
    const int* __restrict__ boff, int N, int nb){
  const int i = blockIdx.x*1024 + threadIdx.x;
  if (i < N) rp[i] += boff[blockIdx.x];
  if (i == 0) rp[N] = boff[nb];
}
__global__ void fill_k(const int* __restrict__ src, const int* __restrict__ dst, int E,
                       int* __restrict__ pos, int* __restrict__ col){
  int e = blockIdx.x*blockDim.x + threadIdx.x;
  if (e < E){
    int d = dst[e];
    int p = atomicAdd(&pos[d], 1);
    col[p] = src[e];
  }
}
// canonical per-row order: wave-per-node 64-wide bitonic sort in registers.
// fill_k's atomic slot order varies per replay; sorted rows => bit-identical
// downstream fp sums. deg>64 (P~1e-20): deterministic lane-0 fallback.
__global__ __launch_bounds__(256) void sortrow_k(const int* __restrict__ rp,
                                                 int* __restrict__ col, int N){
  const int lane = threadIdx.x & 63;
  const int n = blockIdx.x*4 + (threadIdx.x >> 6);
  if (n >= N) return;
  const int b = rp[n], e = rp[n+1];
  const int deg = e - b;
  if (deg <= 1) return;
  if (deg <= 64){
    int v = (lane < deg) ? col[b + lane] : 0x7fffffff;
#pragma unroll
    for (int k = 2; k <= 64; k <<= 1){
#pragma unroll
      for (int j = k >> 1; j > 0; j >>= 1){
        const int other = __shfl_xor(v, j);
        const bool up = ((lane & k) == 0);
        const bool takeMin = (((lane & j) == 0) == up);
        v = takeMin ? min(v, other) : max(v, other);
      }
    }
    if (lane < deg) col[b + lane] = v;
  } else if (lane == 0){
    for (int i = b + 1; i < e; ++i){
      const int key = col[i];
      int j = i - 1;
      while (j >= b && col[j] > key){ col[j+1] = col[j]; --j; }
      col[j+1] = key;
    }
  }
}

// ----------------------------- GEMM  h = A(Nx128) @ W(128xM) ----------------
// 64x64 tile per 256-thread block, K staged in 2 halves of 64 (32KB LDS).
// BN(scale,shift)+ReLU optionally applied to A while staging. Epilogue
// computes per-head attention dots (block (.,y) owns head y fully).
__global__ __launch_bounds__(256) void gemm_k(const float* __restrict__ A,
    const float* __restrict__ W, float* __restrict__ O,
    const float* __restrict__ bnsc, const float* __restrict__ bnsh,
    const float* __restrict__ atts, const float* __restrict__ attd,
    float* __restrict__ als, float* __restrict__ ald, int N, int M){
  __shared__ float xs[64][64];    // [k'][swizzled row]
  __shared__ float wsh[64][64];   // [k'][col]
  const int tid = threadIdx.x;
  const int row0 = blockIdx.x*64, col0 = blockIdx.y*64;
  const int HS = gridDim.y;       // heads == col blocks
  const int ty = tid >> 4, tx = tid & 15;
  float acc[4][4] = {};

  for (int kk = 0; kk < 128; kk += 64){
    // stage W rows kk..kk+63 (4 x float4 per thread = 64x64)
    {
      const int c4 = (tid & 15)*4;
#pragma unroll
      for (int p = 0; p < 4; ++p){
        const int k = p*16 + (tid >> 4);
        *reinterpret_cast<float4*>(&wsh[k][c4]) =
            *reinterpret_cast<const float4*>(&W[(size_t)(kk + k)*M + col0 + c4]);
      }
    }
    // stage x transposed with XOR swizzle
    {
      const int k4 = (tid & 15)*4;           // local k' base (0..60)
      const int rbase = tid >> 4;            // 0..15
#pragma unroll
      for (int p = 0; p < 4; ++p){
        const int rr = p*16 + rbase;
        int gr = row0 + rr; if (gr > N-1) gr = N-1;
        float4 xv = *reinterpret_cast<const float4*>(&A[(size_t)gr*128 + kk + k4]);
        float xq[4] = {xv.x, xv.y, xv.z, xv.w};
        if (bnsc != nullptr){
#pragma unroll
          for (int q = 0; q < 4; ++q)
            xq[q] = fmaxf(xq[q]*bnsc[kk + k4 + q] + bnsh[kk + k4 + q], 0.f);
        }
#pragma unroll
        for (int q = 0; q < 4; ++q){
          const int k = k4 + q;
          const int swz = ((k >> 2) & 15) << 2;
          xs[k][rr ^ swz] = xq[q];
        }
      }
    }
    __syncthreads();
#pragma unroll 8
    for (int k = 0; k < 64; ++k){
      const int swz = ((k >> 2) & 15) << 2;
      const int xr = (ty*4) ^ swz;
      const float4 xv = *reinterpret_cast<const float4*>(&xs[k][xr]);
      const float2 w0 = *reinterpret_cast<const float2*>(&wsh[k][2*tx]);
      const float2 w1 = *reinterpret_cast<const float2*>(&wsh[k][32 + 2*tx]);
      const float xq[4] = {xv.x, xv.y, xv.z, xv.w};
#pragma unroll
      for (int i = 0; i < 4; ++i){
        acc[i][0] += xq[i]*w0.x;
        acc[i][1] += xq[i]*w0.y;
        acc[i][2] += xq[i]*w1.x;
        acc[i][3] += xq[i]*w1.y;
      }
    }
    __syncthreads();
  }
  // ---- alpha epilogue: per-head dots with att_src/att_dst ----
  {
    const float* as = atts + col0;
    const float* ad = attd + col0;
    const float a_s0 = as[2*tx],      a_s1 = as[2*tx + 1];
    const float a_s2 = as[32 + 2*tx], a_s3 = as[33 + 2*tx];
    const float a_d0 = ad[2*tx],      a_d1 = ad[2*tx + 1];
    const float a_d2 = ad[32 + 2*tx], a_d3 = ad[33 + 2*tx];
#pragma unroll
    for (int i = 0; i < 4; ++i){
      float ps = acc[i][0]*a_s0 + acc[i][1]*a_s1 + acc[i][2]*a_s2 + acc[i][3]*a_s3;
      float pd = acc[i][0]*a_d0 + acc[i][1]*a_d1 + acc[i][2]*a_d2 + acc[i][3]*a_d3;
#pragma unroll
      for (int o = 1; o < 16; o <<= 1){
        ps += __shfl_xor(ps, o);
        pd += __shfl_xor(pd, o);
      }
      const int r = row0 + ty*4 + i;
      if (tx == 0 && r < N){
        als[(size_t)r*HS + blockIdx.y] = ps;
        ald[(size_t)r*HS + blockIdx.y] = pd;
      }
    }
  }
#pragma unroll
  for (int i = 0; i < 4; ++i){
    const int r = row0 + ty*4 + i;
    if (r < N){
      float2* o2 = reinterpret_cast<float2*>(&O[(size_t)r*M + col0]);
      o2[tx]      = make_float2(acc[i][0], acc[i][1]);
      o2[16 + tx] = make_float2(acc[i][2], acc[i][3]);
    }
  }
}

// -------- per-node softmax over incoming edges + weighted gather-sum --------
// Phase 1: online (max,sum) over edges, wave-parallel.
// Phase 2: row gather; 32 lanes x float4 = full row => 2 edges/iter (H=2),
//          16 lanes x float4 = full row => 4 edges/iter (H=1).
//          Self-term carried only by edge-group 0.
template<int H>
__global__ __launch_bounds__(256) void agg_k(const float* __restrict__ h,
    const float* __restrict__ als, const float* __restrict__ ald,
    const int* __restrict__ rp, const int* __restrict__ col,
    const float* __restrict__ bias, float* __restrict__ out, int N){
  const int lane = threadIdx.x & 63;
  const int n = blockIdx.x*4 + (threadIdx.x >> 6);
  if (n >= N) return;
  const int beg = rp[n], end = rp[n+1];
  float as0, as1 = 0.f, ad0, ad1 = 0.f;
  if (H == 2){
    const float2 a = ((const float2*)als)[n];
    const float2 d = ((const float2*)ald)[n];
    as0 = a.x; as1 = a.y; ad0 = d.x; ad1 = d.y;
  } else { as0 = als[n]; ad0 = ald[n]; }
  const float self0 = lrelu(as0 + ad0);
  const float self1 = (H == 2) ? lrelu(as1 + ad1) : 0.f;
  // ---- phase 1: online softmax (m, p) per lane, then wave combine ----
  float m0 = self0, p0 = (lane == 0) ? 1.f : 0.f;
  float m1 = self1, p1 = (lane == 0) ? 1.f : 0.f;
  for (int i = beg + lane; i < end; i += 64){
    const int s = col[i];
    if (H == 2){
      const float2 a = ((const float2*)als)[s];
      const float al0 = lrelu(a.x + ad0);
      const float al1 = lrelu(a.y + ad1);
      if (al0 > m0){ p0 = p0*__expf(m0 - al0) + 1.f; m0 = al0; }
      else p0 += __expf(al0 - m0);
      if (al1 > m1){ p1 = p1*__expf(m1 - al1) + 1.f; m1 = al1; }
      else p1 += __expf(al1 - m1);
    } else {
      const float al0 = lrelu(als[s] + ad0);
      if (al0 > m0){ p0 = p0*__expf(m0 - al0) + 1.f; m0 = al0; }
      else p0 += __expf(al0 - m0);
    }
  }
#pragma unroll
  for (int o = 1; o < 64; o <<= 1){
    const float om0 = __shfl_xor(m0, o), op0 = __shfl_xor(p0, o);
    const float nm0 = fmaxf(m0, om0);
    p0 = p0*__expf(m0 - nm0) + op0*__expf(om0 - nm0); m0 = nm0;
    if (H == 2){
      const float om1 = __shfl_xor(m1, o), op1 = __shfl_xor(p1, o);
      const float nm1 = fmaxf(m1, om1);
      p1 = p1*__expf(m1 - nm1) + op1*__expf(om1 - nm1); m1 = nm1;
    }
  }
  const float inv0 = 1.f/(p0 + 1e-16f);
  const float inv1 = (H == 2) ? 1.f/(p1 + 1e-16f) : 0.f;

  // ---- phase 2: gather; float4 per lane ----
  const float4* h4 = (const float4*)h;
  if (H == 2){
    const int sub = lane & 31;            // owns cols 4*sub..4*sub+3
    const int half = lane >> 5;           // which edge of the pair
    const float csel = (sub < 16) ? __expf(self0 - m0)*inv0 : __expf(self1 - m1)*inv1;
    const float cs = (half == 0) ? csel : 0.f;   // self only in group 0
    const float4 hv = h4[(size_t)n*32 + sub];
    float ax = cs*hv.x, ay = cs*hv.y, az = cs*hv.z, aw = cs*hv.w;
    for (int base = beg; base < end; base += 64){
      const int idx = base + lane;
      int sv = n; float c0v = 0.f, c1v = 0.f;
      if (idx < end){
        sv = col[idx];
        const float2 a = ((const float2*)als)[sv];
        c0v = __expf(lrelu(a.x + ad0) - m0)*inv0;
        c1v = __expf(lrelu(a.y + ad1) - m1)*inv1;
      }
      const int cnt = min(64, end - base);
      const int iters = (cnt + 1) >> 1;
      for (int j = 0; j < iters; ++j){
        const int e = 2*j + half;
        const int   src = __shfl(sv, e);
        const float cc0 = __shfl(c0v, e);
        const float cc1 = __shfl(c1v, e);
        const float c = (sub < 16) ? cc0 : cc1;
        const float4 hvv = h4[(size_t)src*32 + sub];
        ax += c*hvv.x; ay += c*hvv.y; az += c*hvv.z; aw += c*hvv.w;
      }
    }
    // combine the two half-wave partials (same cols, different edges)
    ax += __shfl_xor(ax, 32); ay += __shfl_xor(ay, 32);
    az += __shfl_xor(az, 32); aw += __shfl_xor(aw, 32);
    if (lane < 32){
      const float4 bv = ((const float4*)bias)[sub];
      float4 o4 = make_float4(ax + bv.x, ay + bv.y, az + bv.z, aw + bv.w);
      ((float4*)out)[(size_t)n*32 + sub] = o4;
    }
  } else {
    const int sub = lane & 15;            // owns cols 4*sub..4*sub+3 (of 64)
    const int quad = lane >> 4;           // which edge of the quad
    const float cs = (quad == 0) ? __expf(self0 - m0)*inv0 : 0.f;  // self once
    const float4 hv = h4[(size_t)n*16 + sub];
    float ax = cs*hv.x, ay = cs*hv.y, az = cs*hv.z, aw = cs*hv.w;
    for (int base = beg; base < end; base += 64){
      const int idx = base + lane;
      int sv = n; float c0v = 0.f;
      if (idx < end){
        sv = col[idx];
        c0v = __expf(lrelu(als[sv] + ad0) - m0)*inv0;
      }
      const int cnt = min(64, end - base);
      const int iters = (cnt + 3) >> 2;
      for (int j = 0; j < iters; ++j){
        const int e = 4*j + quad;
        const int   src = __shfl(sv, e);
        const float cc  = __shfl(c0v, e);
        const float4 hvv = h4[(size_t)src*16 + sub];
        ax += cc*hvv.x; ay += cc*hvv.y; az += cc*hvv.z; aw += cc*hvv.w;
      }
    }
    ax += __shfl_xor(ax, 16); ay += __shfl_xor(ay, 16);
    az += __shfl_xor(az, 16); aw += __shfl_xor(aw, 16);
    ax += __shfl_xor(ax, 32); ay += __shfl_xor(ay, 32);
    az += __shfl_xor(az, 32); aw += __shfl_xor(aw, 32);
    if (lane < 16){
      const float4 bv = ((const float4*)bias)[sub];
      float4 o4 = make_float4(ax + bv.x, ay + bv.y, az + bv.z, aw + bv.w);
      ((float4*)out)[(size_t)n*16 + sub] = o4;
    }
  }
}

// ------------------------------- batch norm ---------------------------------
// Deterministic two-stage: per-block partials (fixed slots) + fixed-tree reduce.
__global__ __launch_bounds__(128) void bn_stats_k(const float* __restrict__ x, int N,
                                                  double* __restrict__ part){
  const int c = threadIdx.x;           // 128 columns
  double s = 0.0, s2 = 0.0;
  for (int r = blockIdx.x; r < N; r += gridDim.x){
    const float v = x[(size_t)r*128 + c];
    s += v; s2 += (double)v*(double)v;
  }
  part[(size_t)blockIdx.x*256 + c]       = s;
  part[(size_t)blockIdx.x*256 + 128 + c] = s2;
}
// block c reduces column c's partials in a fixed tree; emits scale/shift.
__global__ __launch_bounds__(64) void bnfin_k(const double* __restrict__ part,
    const float* __restrict__ g, const float* __restrict__ b,
    float* __restrict__ sc, float* __restrict__ sh, int N){
  const int c = blockIdx.x;
  const int l = threadIdx.x;
  double s = 0.0, s2 = 0.0;
  for (int i = l; i < BN_BLOCKS; i += 64){
    s  += part[(size_t)i*256 + c];
    s2 += part[(size_t)i*256 + 128 + c];
  }
#pragma unroll
  for (int o = 32; o > 0; o >>= 1){
    s  += __shfl_xor(s, o);
    s2 += __shfl_xor(s2, o);
  }
  if (l == 0){
    const double mu  = s/(double)N;
    const double var = s2/(double)N - mu*mu;
    const float scale = rsqrtf((float)var + 1e-5f)*g[c];
    sc[c] = scale;
    sh[c] = b[c] - (float)mu*scale;
  }
}

// ------------------------------ readout -------------------------------------
__global__ __launch_bounds__(256) void pred_k(const float* __restrict__ f0,
    const float* __restrict__ f1, const float* __restrict__ Wo,
    float* __restrict__ pred, int N){
  const int lane = threadIdx.x & 63;
  const int n = blockIdx.x*4 + (threadIdx.x >> 6);
  if (n >= N) return;
  const float xf = (f0[(size_t)n*64 + lane] + f1[(size_t)n*64 + lane])*0.5f;
  const float p = wsum(xf*Wo[lane]);
  if (lane == 0) pred[n] = p;
}
__global__ __launch_bounds__(64) void segred_k(const float* __restrict__ pred,
    const int* __restrict__ bid, const float* __restrict__ bo,
    float* __restrict__ out, int N){
  const int g = blockIdx.x;
  int lo = 0, hi = N;
  while (lo < hi){ const int mid = (lo + hi) >> 1; if (bid[mid] < g) lo = mid + 1; else hi = mid; }
  const int s0 = lo;
  hi = N;
  while (lo < hi){ const int mid = (lo + hi) >> 1; if (bid[mid] < g + 1) lo = mid + 1; else hi = mid; }
  const int s1 = lo;
  float s = 0.f;
  for (int i = s0 + threadIdx.x; i < s1; i += 64) s += pred[i];
  s = wsum(s);
  if (threadIdx.x == 0)
    out[g] = (s1 > s0) ? s/(float)(s1 - s0) + bo[0] : 0.f;
}

// ---------------------------------------------------------------------------
extern "C" void kernel_launch(void* const* d_in, const int* in_sizes, int n_in,
                              void* d_out, int out_size, void* d_ws, size_t ws_size,
                              hipStream_t stream) {
  const int N = in_sizes[0]/128;      // 50000
  const int E = in_sizes[1]/2;        // 800000
  const int G = out_size;             // 512

  const float* x    = (const float*)d_in[0];
  const int*   eisc = (const int*)d_in[1];
  const int*   eifc = (const int*)d_in[2];
  const int*   bid  = (const int*)d_in[3];
  const float* Ws   = (const float*)d_in[4];
  const float* atts = (const float*)d_in[5];
  const float* attd = (const float*)d_in[6];
  const float* bgat = (const float*)d_in[7];
  const float* bng  = (const float*)d_in[8];
  const float* bnb  = (const float*)d_in[9];
  const float* Wf   = (const float*)d_in[10];
  const float* afs  = (const float*)d_in[11];
  const float* afd  = (const float*)d_in[12];
  const float* bf   = (const float*)d_in[13];
  const float* Wo   = (const float*)d_in[14];
  const float* bo   = (const float*)d_in[15];
  float* out = (float*)d_out;

  char* wp = (char*)d_ws;
  auto grab = [&](size_t bytes)->char* {
    uintptr_t p = ((uintptr_t)wp + 255) & ~(uintptr_t)255;
    wp = (char*)(p + bytes);
    return (char*)p;
  };
  // zeroed region (contiguous, single zero kernel): CSR counters only
  char* zbase = (char*)(((uintptr_t)d_ws + 255) & ~(uintptr_t)255);
  int*    cntA  = (int*)grab((size_t)N*4);
  int*    cntB  = (int*)grab((size_t)N*4);
  const int zwords = (int)(((size_t)(wp - zbase)) / 4);
  // non-zeroed scratch
  double* part  = (double*)grab((size_t)BN_BLOCKS*256*8);
  int*   rp_sc  = (int*)grab((size_t)(N+1)*4);
  int*   rp_fc  = (int*)grab((size_t)(N+1)*4);
  int*   col_sc = (int*)grab((size_t)E*4);
  int*   col_fc = (int*)grab((size_t)E*4);
  int*   bsum   = (int*)grab(64*4);
  int*   boff   = (int*)grab(65*4);
  float* hb     = (float*)grab((size_t)N*128*4);
  float* x0b    = (float*)grab((size_t)N*128*4);
  float* x1b    = (float*)grab((size_t)N*128*4);
  float* alsb   = (float*)grab((size_t)N*2*4);
  float* aldb   = (float*)grab((size_t)N*2*4);
  float* bnsc   = (float*)grab((size_t)6*128*4);
  float* bnsh   = (float*)grab((size_t)6*128*4);
  float* pred   = alsb;               // reuse (dead by readout time)
  (void)ws_size; (void)n_in;

  zero_k<<<(zwords + 255)/256, 256, 0, stream>>>((int*)zbase, zwords);

  const int EB = (E + 255)/256;
  const int NB = (N + 255)/256;
  const int SB = (N + 1023)/1024;     // 49
  const int NB4 = (N + 3)/4;          // wave-per-node grids
  // ---- CSR for sc edge set (dst-major) ----
  count_k<<<EB, 256, 0, stream>>>(eisc + E, E, cntA);
  count_k<<<EB, 256, 0, stream>>>(eifc + E, E, cntB);
  scanA_k<<<SB, 1024, 0, stream>>>(cntA, rp_sc, bsum, N);
  scanB_k<<<1, 64, 0, stream>>>(bsum, boff, SB);
  scanC_k<<<SB, 1024, 0, stream>>>(rp_sc, boff, N, SB);
  copy_k<<<NB, 256, 0, stream>>>(rp_sc, cntA, N);
  fill_k<<<EB, 256, 0, stream>>>(eisc, eisc + E, E, cntA, col_sc);
  sortrow_k<<<NB4, 256, 0, stream>>>(rp_sc, col_sc, N);
  // ---- CSR for fc edge set ----
  scanA_k<<<SB, 1024, 0, stream>>>(cntB, rp_fc, bsum, N);
  scanB_k<<<1, 64, 0, stream>>>(bsum, boff, SB);
  scanC_k<<<SB, 1024, 0, stream>>>(rp_fc, boff, N, SB);
  copy_k<<<NB, 256, 0, stream>>>(rp_fc, cntB, N);
  fill_k<<<EB, 256, 0, stream>>>(eifc, eifc + E, E, cntB, col_fc);
  sortrow_k<<<NB4, 256, 0, stream>>>(rp_fc, col_fc, N);

  const dim3 gg2((N + 63)/64, 2), gg1((N + 63)/64, 1);
  const float* cur0 = x;
  const float* cur1 = x;
  for (int l = 0; l < NLAYERS; ++l){
    const float* Wl = Ws + (size_t)l*128*128;
    const float* as = atts + l*128;
    const float* ad = attd + l*128;
    const float* bg = bgat + l*128;
    // BN params of PREVIOUS layer fused into this gemm's A staging (l==0: none)
    const float* sc0 = (l == 0) ? nullptr : bnsc + ((l-1)*2 + 0)*128;
    const float* sh0 = (l == 0) ? nullptr : bnsh + ((l-1)*2 + 0)*128;
    const float* sc1 = (l == 0) ? nullptr : bnsc + ((l-1)*2 + 1)*128;
    const float* sh1 = (l == 0) ? nullptr : bnsh + ((l-1)*2 + 1)*128;

    // branch 0 (sc)
    gemm_k<<<gg2, 256, 0, stream>>>(cur0, Wl, hb, sc0, sh0, as, ad, alsb, aldb, N, 128);
    agg_k<2><<<NB4, 256, 0, stream>>>(hb, alsb, aldb, rp_sc, col_sc, bg, x0b, N);
    bn_stats_k<<<BN_BLOCKS, 128, 0, stream>>>(x0b, N, part);
    bnfin_k<<<128, 64, 0, stream>>>(part, bng + l*128, bnb + l*128,
                                    bnsc + (l*2 + 0)*128, bnsh + (l*2 + 0)*128, N);
    // branch 1 (fc): layer 0 shares x AND W -> reuse hb/alsb/aldb from branch 0
    if (l != 0)
      gemm_k<<<gg2, 256, 0, stream>>>(cur1, Wl, hb, sc1, sh1, as, ad, alsb, aldb, N, 128);
    agg_k<2><<<NB4, 256, 0, stream>>>(hb, alsb, aldb, rp_fc, col_fc, bg, x1b, N);
    bn_stats_k<<<BN_BLOCKS, 128, 0, stream>>>(x1b, N, part);
    bnfin_k<<<128, 64, 0, stream>>>(part, bng + l*128, bnb + l*128,
                                    bnsc + (l*2 + 1)*128, bnsh + (l*2 + 1)*128, N);
    cur0 = x0b;
    cur1 = x1b;
  }
  // final convs (H=1, C=64); BN of layer 2 fused into gemm A staging.
  // agg outputs reuse x0b/x1b as [N][64] (safe: gemm consumed them already).
  gemm_k<<<gg1, 256, 0, stream>>>(cur0, Wf, hb, bnsc + 4*128, bnsh + 4*128,
                                  afs, afd, alsb, aldb, N, 64);
  agg_k<1><<<NB4, 256, 0, stream>>>(hb, alsb, aldb, rp_sc, col_sc, bf, x0b, N);

  gemm_k<<<gg1, 256, 0, stream>>>(cur1, Wf, hb, bnsc + 5*128, bnsh + 5*128,
                                  afs, afd, alsb, aldb, N, 64);
  agg_k<1><<<NB4, 256, 0, stream>>>(hb, alsb, aldb, rp_fc, col_fc, bf, x1b, N);

  // fuse + readout + per-graph mean (atomic-free: sorted-segment reduce)
  pred_k<<<NB4, 256, 0, stream>>>(x0b, x1b, Wo, pred, N);
  segred_k<<<G, 64, 0, stream>>>(pred, bid, bo, out, N);
}

// Round 11
// 1167.885 us; speedup vs baseline: 1.3044x; 1.1657x over previous
//
#include <hip/hip_runtime.h>
#include <cstdint>
#include <cstddef>

// ---------------------------------------------------------------------------
// GATFuse. R5 -> R6 changes (dispatch-count / serialization attack):
//  - branch-merged dispatches: per-layer {gemm x2, agg x2, bn_stats x2,
//    bnfin x2} each become ONE launch (blockIdx.y/z selects branch).
//    Separate hb0/hb1 (+als/ald per branch) remove the false hb dependency.
//    ws_size checked; serial fallback (hb1=hb0 alias, zbase loop) if small.
//  - CSR build batched over both edge sets (count/scanA/B/C/fill/sortrow x1);
//    copy_k eliminated (scanC writes pos directly).
//  - pred_k folded into segred_k (mean(xf@Wo) == (sum xf/cnt)@Wo).
// Kernel bodies (gemm/agg/sort/bn) unchanged from verified R5.
// ---------------------------------------------------------------------------

#define NLAYERS 3
#define BN_BLOCKS 256

__device__ __forceinline__ float lrelu(float a){ return a > 0.f ? a : 0.2f*a; }

__device__ __forceinline__ float wsum(float v){
#pragma unroll
  for (int o = 32; o > 0; o >>= 1) v += __shfl_xor(v, o);
  return v;
}

// ----------------------------- utility kernels -----------------------------
__global__ void zero_k(int* __restrict__ p, int n){
  int i = blockIdx.x*blockDim.x + threadIdx.x;
  if (i < n) p[i] = 0;
}
// batched over both edge sets via blockIdx.y
__global__ void count2_k(const int* __restrict__ d0, const int* __restrict__ d1,
                         int E, int* __restrict__ c0, int* __restrict__ c1){
  const int e = blockIdx.x*blockDim.x + threadIdx.x;
  const int* d = blockIdx.y ? d1 : d0;
  int* c = blockIdx.y ? c1 : c0;
  if (e < E) atomicAdd(&c[d[e]], 1);
}
__global__ __launch_bounds__(1024) void scanA2_k(const int* __restrict__ c0,
    const int* __restrict__ c1, int* __restrict__ r0, int* __restrict__ r1,
    int* __restrict__ bsum, int N){
  const int z = blockIdx.y;
  const int* cnt = z ? c1 : c0;
  int* excl = z ? r1 : r0;
  __shared__ int wpart[16];
  const int tid = threadIdx.x, lane = tid & 63, w = tid >> 6;
  const int i = blockIdx.x*1024 + tid;
  const int v = (i < N) ? cnt[i] : 0;
  int s = v;
#pragma unroll
  for (int o = 1; o < 64; o <<= 1){ int t = __shfl_up(s, o); if (lane >= o) s += t; }
  if (lane == 63) wpart[w] = s;
  __syncthreads();
  if (w == 0){
    int t = (lane < 16) ? wpart[lane] : 0;
#pragma unroll
    for (int o = 1; o < 16; o <<= 1){ int u = __shfl_up(t, o); if (lane >= o) t += u; }
    if (lane < 16) wpart[lane] = t;
  }
  __syncthreads();
  const int woff = (w > 0) ? wpart[w-1] : 0;
  const int incl = s + woff;
  if (i < N) excl[i] = incl - v;
  if (tid == 1023) bsum[z*64 + blockIdx.x] = incl;
}
__global__ void scanB2_k(const int* __restrict__ bsum, int* __restrict__ boff, int nb){
  const int z = blockIdx.y;
  const int lane = threadIdx.x;
  const int v = (lane < nb) ? bsum[z*64 + lane] : 0;
  int s = v;
#pragma unroll
  for (int o = 1; o < 64; o <<= 1){ int t = __shfl_up(s, o); if (lane >= o) s += t; }
  if (lane < nb) boff[z*65 + lane] = s - v;
  if (lane == nb-1) boff[z*65 + nb] = s;
}
// adds block offsets AND writes the fill cursor array (replaces copy_k)
__global__ __launch_bounds__(1024) void scanC2_k(int* __restrict__ r0,
    int* __restrict__ r1, int* __restrict__ p0, int* __restrict__ p1,
    const int* __restrict__ boff, int N, int nb){
  const int z = blockIdx.y;
  int* rp  = z ? r1 : r0;
  int* pos = z ? p1 : p0;
  const int i = blockIdx.x*1024 + threadIdx.x;
  if (i < N){
    const int v = rp[i] + boff[z*65 + blockIdx.x];
    rp[i] = v;
    pos[i] = v;
  }
  if (i == 0) rp[N] = boff[z*65 + nb];
}
__global__ void fill2_k(const int* __restrict__ e0, const int* __restrict__ e1,
    int E, int* __restrict__ p0, int* __restrict__ p1,
    int* __restrict__ col0, int* __restrict__ col1){
  const int e = blockIdx.x*blockDim.x + threadIdx.x;
  const int* ei = blockIdx.y ? e1 : e0;
  int* pos = blockIdx.y ? p1 : p0;
  int* col = blockIdx.y ? col1 : col0;
  if (e < E){
    const int d = ei[E + e];        // dst row
    const int p = atomicAdd(&pos[d], 1);
    col[p] = ei[e];                 // src
  }
}
// canonical per-row order: wave-per-node 64-wide bitonic sort in registers.
// batched over both edge sets via blockIdx.y. deg>64: lane-0 fallback.
__global__ __launch_bounds__(256) void sortrow2_k(const int* __restrict__ r0,
    const int* __restrict__ r1, int* __restrict__ c0, int* __restrict__ c1, int N){
  const int z = blockIdx.y;
  const int* rp = z ? r1 : r0;
  int* col = z ? c1 : c0;
  const int lane = threadIdx.x & 63;
  const int n = blockIdx.x*4 + (threadIdx.x >> 6);
  if (n >= N) return;
  const int b = rp[n], e = rp[n+1];
  const int deg = e - b;
  if (deg <= 1) return;
  if (deg <= 64){
    int v = (lane < deg) ? col[b + lane] : 0x7fffffff;
#pragma unroll
    for (int k = 2; k <= 64; k <<= 1){
#pragma unroll
      for (int j = k >> 1; j > 0; j >>= 1){
        const int other = __shfl_xor(v, j);
        const bool up = ((lane & k) == 0);
        const bool takeMin = (((lane & j) == 0) == up);
        v = takeMin ? min(v, other) : max(v, other);
      }
    }
    if (lane < deg) col[b + lane] = v;
  } else if (lane == 0){
    for (int i = b + 1; i < e; ++i){
      const int key = col[i];
      int j = i - 1;
      while (j >= b && col[j] > key){ col[j+1] = col[j]; --j; }
      col[j+1] = key;
    }
  }
}

// ----------------------------- GEMM  h = A(Nx128) @ W(128xM) ----------------
// 64x64 tile, K-split 2x64 (32KB LDS). Branch selected by blockIdx.z + zbase.
// BN(scale,shift)+ReLU applied to A while staging. Alpha epilogue per head.
__global__ __launch_bounds__(256) void gemm_k(
    const float* __restrict__ A0, const float* __restrict__ A1,
    const float* __restrict__ W, float* __restrict__ O0, float* __restrict__ O1,
    const float* __restrict__ scA, const float* __restrict__ shA,
    const float* __restrict__ scB, const float* __restrict__ shB,
    const float* __restrict__ atts, const float* __restrict__ attd,
    float* __restrict__ als0, float* __restrict__ ald0,
    float* __restrict__ als1, float* __restrict__ ald1,
    int N, int M, int zbase){
  const int br = blockIdx.z + zbase;
  const float* A = br ? A1 : A0;
  float* O = br ? O1 : O0;
  const float* bnsc = br ? scB : scA;
  const float* bnsh = br ? shB : shA;
  float* als = br ? als1 : als0;
  float* ald = br ? ald1 : ald0;

  __shared__ float xs[64][64];    // [k'][swizzled row]
  __shared__ float wsh[64][64];   // [k'][col]
  const int tid = threadIdx.x;
  const int row0 = blockIdx.x*64, col0 = blockIdx.y*64;
  const int HS = gridDim.y;       // heads == col blocks
  const int ty = tid >> 4, tx = tid & 15;
  float acc[4][4] = {};

  for (int kk = 0; kk < 128; kk += 64){
    {
      const int c4 = (tid & 15)*4;
#pragma unroll
      for (int p = 0; p < 4; ++p){
        const int k = p*16 + (tid >> 4);
        *reinterpret_cast<float4*>(&wsh[k][c4]) =
            *reinterpret_cast<const float4*>(&W[(size_t)(kk + k)*M + col0 + c4]);
      }
    }
    {
      const int k4 = (tid & 15)*4;
      const int rbase = tid >> 4;
#pragma unroll
      for (int p = 0; p < 4; ++p){
        const int rr = p*16 + rbase;
        int gr = row0 + rr; if (gr > N-1) gr = N-1;
        float4 xv = *reinterpret_cast<const float4*>(&A[(size_t)gr*128 + kk + k4]);
        float xq[4] = {xv.x, xv.y, xv.z, xv.w};
        if (bnsc != nullptr){
#pragma unroll
          for (int q = 0; q < 4; ++q)
            xq[q] = fmaxf(xq[q]*bnsc[kk + k4 + q] + bnsh[kk + k4 + q], 0.f);
        }
#pragma unroll
        for (int q = 0; q < 4; ++q){
          const int k = k4 + q;
          const int swz = ((k >> 2) & 15) << 2;
          xs[k][rr ^ swz] = xq[q];
        }
      }
    }
    __syncthreads();
#pragma unroll 8
    for (int k = 0; k < 64; ++k){
      const int swz = ((k >> 2) & 15) << 2;
      const int xr = (ty*4) ^ swz;
      const float4 xv = *reinterpret_cast<const float4*>(&xs[k][xr]);
      const float2 w0 = *reinterpret_cast<const float2*>(&wsh[k][2*tx]);
      const float2 w1 = *reinterpret_cast<const float2*>(&wsh[k][32 + 2*tx]);
      const float xq[4] = {xv.x, xv.y, xv.z, xv.w};
#pragma unroll
      for (int i = 0; i < 4; ++i){
        acc[i][0] += xq[i]*w0.x;
        acc[i][1] += xq[i]*w0.y;
        acc[i][2] += xq[i]*w1.x;
        acc[i][3] += xq[i]*w1.y;
      }
    }
    __syncthreads();
  }
  // ---- alpha epilogue ----
  {
    const float* as = atts + col0;
    const float* ad = attd + col0;
    const float a_s0 = as[2*tx],      a_s1 = as[2*tx + 1];
    const float a_s2 = as[32 + 2*tx], a_s3 = as[33 + 2*tx];
    const float a_d0 = ad[2*tx],      a_d1 = ad[2*tx + 1];
    const float a_d2 = ad[32 + 2*tx], a_d3 = ad[33 + 2*tx];
#pragma unroll
    for (int i = 0; i < 4; ++i){
      float ps = acc[i][0]*a_s0 + acc[i][1]*a_s1 + acc[i][2]*a_s2 + acc[i][3]*a_s3;
      float pd = acc[i][0]*a_d0 + acc[i][1]*a_d1 + acc[i][2]*a_d2 + acc[i][3]*a_d3;
#pragma unroll
      for (int o = 1; o < 16; o <<= 1){
        ps += __shfl_xor(ps, o);
        pd += __shfl_xor(pd, o);
      }
      const int r = row0 + ty*4 + i;
      if (tx == 0 && r < N){
        als[(size_t)r*HS + blockIdx.y] = ps;
        ald[(size_t)r*HS + blockIdx.y] = pd;
      }
    }
  }
#pragma unroll
  for (int i = 0; i < 4; ++i){
    const int r = row0 + ty*4 + i;
    if (r < N){
      float2* o2 = reinterpret_cast<float2*>(&O[(size_t)r*M + col0]);
      o2[tx]      = make_float2(acc[i][0], acc[i][1]);
      o2[16 + tx] = make_float2(acc[i][2], acc[i][3]);
    }
  }
}

// -------- per-node softmax over incoming edges + weighted gather-sum --------
// Branch selected by blockIdx.y + zbase. Body unchanged from verified R5.
template<int H>
__global__ __launch_bounds__(256) void agg_k(
    const float* __restrict__ h0, const float* __restrict__ h1,
    const float* __restrict__ als0A, const float* __restrict__ ald0A,
    const float* __restrict__ als1A, const float* __restrict__ ald1A,
    const int* __restrict__ rp0, const int* __restrict__ col0A,
    const int* __restrict__ rp1, const int* __restrict__ col1A,
    const float* __restrict__ bias, float* __restrict__ out0,
    float* __restrict__ out1, int N, int zbase){
  const int br = blockIdx.y + zbase;
  const float* h   = br ? h1 : h0;
  const float* als = br ? als1A : als0A;
  const float* ald = br ? ald1A : ald0A;
  const int* rp  = br ? rp1 : rp0;
  const int* col = br ? col1A : col0A;
  float* out = br ? out1 : out0;

  const int lane = threadIdx.x & 63;
  const int n = blockIdx.x*4 + (threadIdx.x >> 6);
  if (n >= N) return;
  const int beg = rp[n], end = rp[n+1];
  float as0, as1 = 0.f, ad0, ad1 = 0.f;
  if (H == 2){
    const float2 a = ((const float2*)als)[n];
    const float2 d = ((const float2*)ald)[n];
    as0 = a.x; as1 = a.y; ad0 = d.x; ad1 = d.y;
  } else { as0 = als[n]; ad0 = ald[n]; }
  const float self0 = lrelu(as0 + ad0);
  const float self1 = (H == 2) ? lrelu(as1 + ad1) : 0.f;
  // ---- phase 1: online softmax (m, p) per lane, then wave combine ----
  float m0 = self0, p0 = (lane == 0) ? 1.f : 0.f;
  float m1 = self1, p1 = (lane == 0) ? 1.f : 0.f;
  for (int i = beg + lane; i < end; i += 64){
    const int s = col[i];
    if (H == 2){
      const float2 a = ((const float2*)als)[s];
      const float al0 = lrelu(a.x + ad0);
      const float al1 = lrelu(a.y + ad1);
      if (al0 > m0){ p0 = p0*__expf(m0 - al0) + 1.f; m0 = al0; }
      else p0 += __expf(al0 - m0);
      if (al1 > m1){ p1 = p1*__expf(m1 - al1) + 1.f; m1 = al1; }
      else p1 += __expf(al1 - m1);
    } else {
      const float al0 = lrelu(als[s] + ad0);
      if (al0 > m0){ p0 = p0*__expf(m0 - al0) + 1.f; m0 = al0; }
      else p0 += __expf(al0 - m0);
    }
  }
#pragma unroll
  for (int o = 1; o < 64; o <<= 1){
    const float om0 = __shfl_xor(m0, o), op0 = __shfl_xor(p0, o);
    const float nm0 = fmaxf(m0, om0);
    p0 = p0*__expf(m0 - nm0) + op0*__expf(om0 - nm0); m0 = nm0;
    if (H == 2){
      const float om1 = __shfl_xor(m1, o), op1 = __shfl_xor(p1, o);
      const float nm1 = fmaxf(m1, om1);
      p1 = p1*__expf(m1 - nm1) + op1*__expf(om1 - nm1); m1 = nm1;
    }
  }
  const float inv0 = 1.f/(p0 + 1e-16f);
  const float inv1 = (H == 2) ? 1.f/(p1 + 1e-16f) : 0.f;

  // ---- phase 2: gather; float4 per lane ----
  const float4* h4 = (const float4*)h;
  if (H == 2){
    const int sub = lane & 31;
    const int half = lane >> 5;
    const float csel = (sub < 16) ? __expf(self0 - m0)*inv0 : __expf(self1 - m1)*inv1;
    const float cs = (half == 0) ? csel : 0.f;   // self only in group 0
    const float4 hv = h4[(size_t)n*32 + sub];
    float ax = cs*hv.x, ay = cs*hv.y, az = cs*hv.z, aw = cs*hv.w;
    for (int base = beg; base < end; base += 64){
      const int idx = base + lane;
      int sv = n; float c0v = 0.f, c1v = 0.f;
      if (idx < end){
        sv = col[idx];
        const float2 a = ((const float2*)als)[sv];
        c0v = __expf(lrelu(a.x + ad0) - m0)*inv0;
        c1v = __expf(lrelu(a.y + ad1) - m1)*inv1;
      }
      const int cnt = min(64, end - base);
      const int iters = (cnt + 1) >> 1;
      for (int j = 0; j < iters; ++j){
        const int e = 2*j + half;
        const int   src = __shfl(sv, e);
        const float cc0 = __shfl(c0v, e);
        const float cc1 = __shfl(c1v, e);
        const float c = (sub < 16) ? cc0 : cc1;
        const float4 hvv = h4[(size_t)src*32 + sub];
        ax += c*hvv.x; ay += c*hvv.y; az += c*hvv.z; aw += c*hvv.w;
      }
    }
    ax += __shfl_xor(ax, 32); ay += __shfl_xor(ay, 32);
    az += __shfl_xor(az, 32); aw += __shfl_xor(aw, 32);
    if (lane < 32){
      const float4 bv = ((const float4*)bias)[sub];
      ((float4*)out)[(size_t)n*32 + sub] =
          make_float4(ax + bv.x, ay + bv.y, az + bv.z, aw + bv.w);
    }
  } else {
    const int sub = lane & 15;
    const int quad = lane >> 4;
    const float cs = (quad == 0) ? __expf(self0 - m0)*inv0 : 0.f;  // self once
    const float4 hv = h4[(size_t)n*16 + sub];
    float ax = cs*hv.x, ay = cs*hv.y, az = cs*hv.z, aw = cs*hv.w;
    for (int base = beg; base < end; base += 64){
      const int idx = base + lane;
      int sv = n; float c0v = 0.f;
      if (idx < end){
        sv = col[idx];
        c0v = __expf(lrelu(als[sv] + ad0) - m0)*inv0;
      }
      const int cnt = min(64, end - base);
      const int iters = (cnt + 3) >> 2;
      for (int j = 0; j < iters; ++j){
        const int e = 4*j + quad;
        const int   src = __shfl(sv, e);
        const float cc  = __shfl(c0v, e);
        const float4 hvv = h4[(size_t)src*16 + sub];
        ax += cc*hvv.x; ay += cc*hvv.y; az += cc*hvv.z; aw += cc*hvv.w;
      }
    }
    ax += __shfl_xor(ax, 16); ay += __shfl_xor(ay, 16);
    az += __shfl_xor(az, 16); aw += __shfl_xor(aw, 16);
    ax += __shfl_xor(ax, 32); ay += __shfl_xor(ay, 32);
    az += __shfl_xor(az, 32); aw += __shfl_xor(aw, 32);
    if (lane < 16){
      const float4 bv = ((const float4*)bias)[sub];
      ((float4*)out)[(size_t)n*16 + sub] =
          make_float4(ax + bv.x, ay + bv.y, az + bv.z, aw + bv.w);
    }
  }
}

// ------------------------------- batch norm ---------------------------------
// Deterministic two-stage, batched over both branches via blockIdx.y.
__global__ __launch_bounds__(128) void bn_stats2_k(const float* __restrict__ x0,
    const float* __restrict__ x1, int N, double* __restrict__ part){
  const int z = blockIdx.y;
  const float* x = z ? x1 : x0;
  double* p = part + (size_t)z*BN_BLOCKS*256;
  const int c = threadIdx.x;
  double s = 0.0, s2 = 0.0;
  for (int r = blockIdx.x; r < N; r += gridDim.x){
    const float v = x[(size_t)r*128 + c];
    s += v; s2 += (double)v*(double)v;
  }
  p[(size_t)blockIdx.x*256 + c]       = s;
  p[(size_t)blockIdx.x*256 + 128 + c] = s2;
}
__global__ __launch_bounds__(64) void bnfin2_k(const double* __restrict__ part,
    const float* __restrict__ g, const float* __restrict__ b,
    float* __restrict__ sc, float* __restrict__ sh, int N){
  const int c = blockIdx.x, z = blockIdx.y;
  const int l = threadIdx.x;
  const double* p = part + (size_t)z*BN_BLOCKS*256;
  double s = 0.0, s2 = 0.0;
  for (int i = l; i < BN_BLOCKS; i += 64){
    s  += p[(size_t)i*256 + c];
    s2 += p[(size_t)i*256 + 128 + c];
  }
#pragma unroll
  for (int o = 32; o > 0; o >>= 1){
    s  += __shfl_xor(s, o);
    s2 += __shfl_xor(s2, o);
  }
  if (l == 0){
    const double mu  = s/(double)N;
    const double var = s2/(double)N - mu*mu;
    const float scale = rsqrtf((float)var + 1e-5f)*g[c];
    sc[z*128 + c] = scale;
    sh[z*128 + c] = b[c] - (float)mu*scale;
  }
}

// ------------------------------ readout -------------------------------------
// fused: per-graph mean of ((f0+f1)/2 @ Wo + bo) == (sum rows / cnt) @ Wo + bo
__global__ __launch_bounds__(64) void segred_k(const float* __restrict__ f0,
    const float* __restrict__ f1, const float* __restrict__ Wo,
    const float* __restrict__ bo, const int* __restrict__ bid,
    float* __restrict__ out, int N){
  const int g = blockIdx.x;
  const int lane = threadIdx.x;
  int lo = 0, hi = N;
  while (lo < hi){ const int mid = (lo + hi) >> 1; if (bid[mid] < g) lo = mid + 1; else hi = mid; }
  const int s0 = lo;
  hi = N;
  while (lo < hi){ const int mid = (lo + hi) >> 1; if (bid[mid] < g + 1) lo = mid + 1; else hi = mid; }
  const int s1 = lo;
  float acc = 0.f;                      // column accumulator (col = lane)
  for (int i = s0; i < s1; ++i)
    acc += f0[(size_t)i*64 + lane] + f1[(size_t)i*64 + lane];
  const float p = wsum(acc*0.5f*Wo[lane]);
  if (lane == 0)
    out[g] = (s1 > s0) ? p/(float)(s1 - s0) + bo[0] : 0.f;
}

// ---------------------------------------------------------------------------
extern "C" void kernel_launch(void* const* d_in, const int* in_sizes, int n_in,
                              void* d_out, int out_size, void* d_ws, size_t ws_size,
                              hipStream_t stream) {
  const int N = in_sizes[0]/128;      // 50000
  const int E = in_sizes[1]/2;        // 800000
  const int G = out_size;             // 512

  const float* x    = (const float*)d_in[0];
  const int*   eisc = (const int*)d_in[1];
  const int*   eifc = (const int*)d_in[2];
  const int*   bid  = (const int*)d_in[3];
  const float* Ws   = (const float*)d_in[4];
  const float* atts = (const float*)d_in[5];
  const float* attd = (const float*)d_in[6];
  const float* bgat = (const float*)d_in[7];
  const float* bng  = (const float*)d_in[8];
  const float* bnb  = (const float*)d_in[9];
  const float* Wf   = (const float*)d_in[10];
  const float* afs  = (const float*)d_in[11];
  const float* afd  = (const float*)d_in[12];
  const float* bf   = (const float*)d_in[13];
  const float* Wo   = (const float*)d_in[14];
  const float* bo   = (const float*)d_in[15];
  float* out = (float*)d_out;

  char* wp = (char*)d_ws;
  auto grab = [&](size_t bytes)->char* {
    uintptr_t p = ((uintptr_t)wp + 255) & ~(uintptr_t)255;
    wp = (char*)(p + bytes);
    return (char*)p;
  };
  // zeroed region (contiguous): CSR counters only
  char* zbase = (char*)(((uintptr_t)d_ws + 255) & ~(uintptr_t)255);
  int*    cntA  = (int*)grab((size_t)N*4);
  int*    cntB  = (int*)grab((size_t)N*4);
  const int zwords = (int)(((size_t)(wp - zbase)) / 4);
  // non-zeroed scratch
  double* part  = (double*)grab((size_t)2*BN_BLOCKS*256*8);
  int*   rp_sc  = (int*)grab((size_t)(N+1)*4);
  int*   rp_fc  = (int*)grab((size_t)(N+1)*4);
  int*   col_sc = (int*)grab((size_t)E*4);
  int*   col_fc = (int*)grab((size_t)E*4);
  int*   bsum   = (int*)grab(128*4);
  int*   boff   = (int*)grab(130*4);
  float* hb0    = (float*)grab((size_t)N*128*4);
  float* x0b    = (float*)grab((size_t)N*128*4);
  float* x1b    = (float*)grab((size_t)N*128*4);
  float* als0   = (float*)grab((size_t)N*2*4);
  float* ald0   = (float*)grab((size_t)N*2*4);
  float* als1   = (float*)grab((size_t)N*2*4);
  float* ald1   = (float*)grab((size_t)N*2*4);
  float* bnsc   = (float*)grab((size_t)6*128*4);
  float* bnsh   = (float*)grab((size_t)6*128*4);
  char*  hb1_p  = grab((size_t)N*128*4);          // optional (big mode)
  const size_t needed = (size_t)(wp - (char*)d_ws);
  const bool big = (ws_size >= needed);
  float* hb1 = big ? (float*)hb1_p : hb0;         // fallback: alias (serial path)
  (void)n_in;

  zero_k<<<(zwords + 255)/256, 256, 0, stream>>>((int*)zbase, zwords);

  const int EB = (E + 255)/256;
  const int SB = (N + 1023)/1024;     // 49
  const int NB4 = (N + 3)/4;          // wave-per-node grids
  // ---- CSR build, both edge sets batched ----
  count2_k<<<dim3(EB,2), 256, 0, stream>>>(eisc + E, eifc + E, E, cntA, cntB);
  scanA2_k<<<dim3(SB,2), 1024, 0, stream>>>(cntA, cntB, rp_sc, rp_fc, bsum, N);
  scanB2_k<<<dim3(1,2), 64, 0, stream>>>(bsum, boff, SB);
  scanC2_k<<<dim3(SB,2), 1024, 0, stream>>>(rp_sc, rp_fc, cntA, cntB, boff, N, SB);
  fill2_k<<<dim3(EB,2), 256, 0, stream>>>(eisc, eifc, E, cntA, cntB, col_sc, col_fc);
  sortrow2_k<<<dim3(NB4,2), 256, 0, stream>>>(rp_sc, rp_fc, col_sc, col_fc, N);

  const float* cur0 = x;
  const float* cur1 = x;
  for (int l = 0; l < NLAYERS; ++l){
    const float* Wl = Ws + (size_t)l*128*128;
    const float* as = atts + l*128;
    const float* ad = attd + l*128;
    const float* bg = bgat + l*128;
    const float* scA = (l == 0) ? nullptr : bnsc + ((l-1)*2 + 0)*128;
    const float* shA = (l == 0) ? nullptr : bnsh + ((l-1)*2 + 0)*128;
    const float* scB = (l == 0) ? nullptr : bnsc + ((l-1)*2 + 1)*128;
    const float* shB = (l == 0) ? nullptr : bnsh + ((l-1)*2 + 1)*128;

    if (l == 0){
      // branches share x and W[0]: one gemm; merged agg reads hb0 for both
      gemm_k<<<dim3((N+63)/64, 2, 1), 256, 0, stream>>>(
          x, x, Wl, hb0, hb0, nullptr, nullptr, nullptr, nullptr,
          as, ad, als0, ald0, als0, ald0, N, 128, 0);
      if (big){
        agg_k<2><<<dim3(NB4, 2), 256, 0, stream>>>(hb0, hb0, als0, ald0, als0, ald0,
            rp_sc, col_sc, rp_fc, col_fc, bg, x0b, x1b, N, 0);
      } else {
        agg_k<2><<<dim3(NB4, 1), 256, 0, stream>>>(hb0, hb0, als0, ald0, als0, ald0,
            rp_sc, col_sc, rp_fc, col_fc, bg, x0b, x1b, N, 0);
        agg_k<2><<<dim3(NB4, 1), 256, 0, stream>>>(hb0, hb0, als0, ald0, als0, ald0,
            rp_sc, col_sc, rp_fc, col_fc, bg, x0b, x1b, N, 1);
      }
    } else if (big){
      gemm_k<<<dim3((N+63)/64, 2, 2), 256, 0, stream>>>(
          cur0, cur1, Wl, hb0, hb1, scA, shA, scB, shB,
          as, ad, als0, ald0, als1, ald1, N, 128, 0);
      agg_k<2><<<dim3(NB4, 2), 256, 0, stream>>>(hb0, hb1, als0, ald0, als1, ald1,
          rp_sc, col_sc, rp_fc, col_fc, bg, x0b, x1b, N, 0);
    } else {
      gemm_k<<<dim3((N+63)/64, 2, 1), 256, 0, stream>>>(
          cur0, cur1, Wl, hb0, hb1, scA, shA, scB, shB,
          as, ad, als0, ald0, als1, ald1, N, 128, 0);
      agg_k<2><<<dim3(NB4, 1), 256, 0, stream>>>(hb0, hb1, als0, ald0, als1, ald1,
          rp_sc, col_sc, rp_fc, col_fc, bg, x0b, x1b, N, 0);
      gemm_k<<<dim3((N+63)/64, 2, 1), 256, 0, stream>>>(
          cur0, cur1, Wl, hb0, hb1, scA, shA, scB, shB,
          as, ad, als0, ald0, als1, ald1, N, 128, 1);
      agg_k<2><<<dim3(NB4, 1), 256, 0, stream>>>(hb0, hb1, als0, ald0, als1, ald1,
          rp_sc, col_sc, rp_fc, col_fc, bg, x0b, x1b, N, 1);
    }
    bn_stats2_k<<<dim3(BN_BLOCKS, 2), 128, 0, stream>>>(x0b, x1b, N, part);
    bnfin2_k<<<dim3(128, 2), 64, 0, stream>>>(part, bng + l*128, bnb + l*128,
                                              bnsc + l*2*128, bnsh + l*2*128, N);
    cur0 = x0b;
    cur1 = x1b;
  }
  // ---- final convs (H=1, C=64); BN of layer 2 fused into gemm A staging ----
  const float* scA = bnsc + 4*128, *shA = bnsh + 4*128;
  const float* scB = bnsc + 5*128, *shB = bnsh + 5*128;
  if (big){
    gemm_k<<<dim3((N+63)/64, 1, 2), 256, 0, stream>>>(
        cur0, cur1, Wf, hb0, hb1, scA, shA, scB, shB,
        afs, afd, als0, ald0, als1, ald1, N, 64, 0);
    agg_k<1><<<dim3(NB4, 2), 256, 0, stream>>>(hb0, hb1, als0, ald0, als1, ald1,
        rp_sc, col_sc, rp_fc, col_fc, bf, x0b, x1b, N, 0);
  } else {
    gemm_k<<<dim3((N+63)/64, 1, 1), 256, 0, stream>>>(
        cur0, cur1, Wf, hb0, hb1, scA, shA, scB, shB,
        afs, afd, als0, ald0, als1, ald1, N, 64, 0);
    agg_k<1><<<dim3(NB4, 1), 256, 0, stream>>>(hb0, hb1, als0, ald0, als1, ald1,
        rp_sc, col_sc, rp_fc, col_fc, bf, x0b, x1b, N, 0);
    gemm_k<<<dim3((N+63)/64, 1, 1), 256, 0, stream>>>(
        cur0, cur1, Wf, hb0, hb1, scA, shA, scB, shB,
        afs, afd, als0, ald0, als1, ald1, N, 64, 1);
    agg_k<1><<<dim3(NB4, 1), 256, 0, stream>>>(hb0, hb1, als0, ald0, als1, ald1,
        rp_sc, col_sc, rp_fc, col_fc, bf, x0b, x1b, N, 1);
  }
  // ---- fused readout: per-graph mean of node predictions ----
  segred_k<<<G, 64, 0, stream>>>(x0b, x1b, Wo, bo, bid, out, N);
}